// Round 1
// baseline (2028.916 us; speedup 1.0000x reference)
//
#include <hip/hip_runtime.h>
#include <math.h>

#define NN 80000
#define NE 2560000
#define BN_EPS 1e-5f

// ---------------- workspace layout (floats) ----------------
#define OFF_DIS   0
#define OFF_COEF  (OFF_DIS + NN)
#define OFF_BUFA  (OFF_COEF + NE)
#define OFF_BUFB  (OFF_BUFA + NN*64)
#define OFF_BUFC  (OFF_BUFB + NN*64)
#define OFF_DEG   (OFF_BUFC + NN*64)      // NN ints
#define OFF_STATS (OFF_DEG + NN)          // 1920 floats
// stats sub-offsets (relative to st)
//   0: xsum[128]   128: xsq[128]
// 256: hsum0[64]   320: hsq0[64]
// 384: hsum1[64]   448: hsq1[64]
// 512: msum0[64]   576: msq0[64]
// 640: msum1[64]   704: msq1[64]
// 768: msum2[32]   800: msq2[32]
// 832: scale0[192] 1024: shift0[192]
// 1216: scale1[192] 1408: shift1[192]
// 1600: sm0[64] 1664: sh0[64]
// 1728: sm1[64] 1792: sh1[64]
// 1856: sm2[32] 1888: sh2[32]

__global__ void k_deg(const int* __restrict__ col, int* __restrict__ deg) {
    int e = blockIdx.x * blockDim.x + threadIdx.x;
    if (e < NE) atomicAdd(&deg[col[e]], 1);
}

__global__ void k_dis(const int* __restrict__ deg, float* __restrict__ dis) {
    int i = blockIdx.x * blockDim.x + threadIdx.x;
    if (i < NN) {
        int d = deg[i];
        dis[i] = d > 0 ? rsqrtf((float)d) : 0.f;
    }
}

__global__ void k_coef(const int* __restrict__ row, const int* __restrict__ col,
                       const float* __restrict__ mask, const float* __restrict__ dis,
                       float* __restrict__ coef) {
    int e = blockIdx.x * blockDim.x + threadIdx.x;
    if (e < NE) coef[e] = dis[row[e]] * dis[col[e]] * mask[e];
}

// column sums/sumsqs of x1 (cols 0-63) and x2 (cols 64-127)
__global__ void __launch_bounds__(256) k_xstats(const float* __restrict__ x1,
                                                const float* __restrict__ x2,
                                                float* __restrict__ st) {
    int wave = threadIdx.x >> 6, lane = threadIdx.x & 63;
    float s1 = 0, q1 = 0, s2 = 0, q2 = 0;
    for (int n = blockIdx.x * 4 + wave; n < NN; n += gridDim.x * 4) {
        float a = x1[n * 64 + lane]; s1 += a; q1 += a * a;
        float b = x2[n * 64 + lane]; s2 += b; q2 += b * b;
    }
    __shared__ float red[4][256];
    red[0][threadIdx.x] = s1; red[1][threadIdx.x] = q1;
    red[2][threadIdx.x] = s2; red[3][threadIdx.x] = q2;
    __syncthreads();
    if (threadIdx.x < 64) {
        int l = threadIdx.x;
        float S1 = red[0][l] + red[0][l + 64] + red[0][l + 128] + red[0][l + 192];
        float Q1 = red[1][l] + red[1][l + 64] + red[1][l + 128] + red[1][l + 192];
        float S2 = red[2][l] + red[2][l + 64] + red[2][l + 128] + red[2][l + 192];
        float Q2 = red[3][l] + red[3][l + 64] + red[3][l + 128] + red[3][l + 192];
        atomicAdd(&st[l], S1);
        atomicAdd(&st[128 + l], Q1);
        atomicAdd(&st[64 + l], S2);
        atomicAdd(&st[192 + l], Q2);
    }
}

// out[n,c] = sum_k concat(x1,x2,rd)[n,k] * W[k,c]   (W is 144x64)
__global__ void __launch_bounds__(256) k_lin0(const float* __restrict__ x1,
                                              const float* __restrict__ x2,
                                              const float* __restrict__ rd,
                                              const float* __restrict__ W,
                                              float* __restrict__ out) {
    __shared__ float Wl[144 * 64];
    for (int i = threadIdx.x; i < 144 * 64; i += 256) Wl[i] = W[i];
    __syncthreads();
    int wave = threadIdx.x >> 6, lane = threadIdx.x & 63;
    for (int n = blockIdx.x * 4 + wave; n < NN; n += gridDim.x * 4) {
        float acc = 0.f;
        const float* a = x1 + (size_t)n * 64;
        #pragma unroll 16
        for (int k = 0; k < 64; k++) acc += a[k] * Wl[k * 64 + lane];
        const float* b = x2 + (size_t)n * 64;
        #pragma unroll 16
        for (int k = 0; k < 64; k++) acc += b[k] * Wl[(64 + k) * 64 + lane];
        const float* c = rd + (size_t)n * 16;
        #pragma unroll 16
        for (int k = 0; k < 16; k++) acc += c[k] * Wl[(128 + k) * 64 + lane];
        out[(size_t)n * 64 + lane] = acc;
    }
}

// one wave per edge; lane = feature. agg[col] += coef * h[row]
__global__ void __launch_bounds__(256) k_scatter(const int* __restrict__ row,
                                                 const int* __restrict__ col,
                                                 const float* __restrict__ coef,
                                                 const float* __restrict__ h,
                                                 float* __restrict__ agg) {
    int t = blockIdx.x * 256 + threadIdx.x;
    int e = t >> 6;
    int f = t & 63;
    if (e < NE) {
        float v = coef[e] * h[(size_t)row[e] * 64 + f];
        atomicAdd(&agg[(size_t)col[e] * 64 + f], v);
    }
}

// in-place: v = elu(agg + bias); also accumulate column stats
__global__ void __launch_bounds__(256) k_postagg(float* __restrict__ agg,
                                                 const float* __restrict__ bias,
                                                 float* __restrict__ sum,
                                                 float* __restrict__ sq) {
    int wave = threadIdx.x >> 6, lane = threadIdx.x & 63;
    float bs = bias[lane];
    float s = 0, q = 0;
    for (int n = blockIdx.x * 4 + wave; n < NN; n += gridDim.x * 4) {
        float v = agg[(size_t)n * 64 + lane] + bs;
        v = v > 0.f ? v : (__expf(v) - 1.f);
        agg[(size_t)n * 64 + lane] = v;
        s += v; q += v * v;
    }
    __shared__ float rs[256], rq[256];
    rs[threadIdx.x] = s; rq[threadIdx.x] = q;
    __syncthreads();
    if (threadIdx.x < 64) {
        int l = threadIdx.x;
        atomicAdd(&sum[l], rs[l] + rs[l + 64] + rs[l + 128] + rs[l + 192]);
        atomicAdd(&sq[l], rq[l] + rq[l + 64] + rq[l + 128] + rq[l + 192]);
    }
}

// finalize 192-col BN: cols 0-127 from xstats, 128-191 from hstats
__global__ void k_bnfin192(const float* __restrict__ xs,
                           const float* __restrict__ hsum, const float* __restrict__ hsq,
                           const float* __restrict__ g, const float* __restrict__ b,
                           float* __restrict__ scale, float* __restrict__ shift) {
    int c = threadIdx.x;  // 192 threads
    float s = c < 128 ? xs[c] : hsum[c - 128];
    float q = c < 128 ? xs[128 + c] : hsq[c - 128];
    float m = s * (1.f / NN);
    float var = q * (1.f / NN) - m * m;
    float sc = g[c] * rsqrtf(var + BN_EPS);
    scale[c] = sc;
    shift[c] = b[c] - m * sc;
}

__global__ void k_bnfin(const float* __restrict__ sum, const float* __restrict__ sq,
                        const float* __restrict__ g, const float* __restrict__ b,
                        float* __restrict__ scale, float* __restrict__ shift) {
    int c = threadIdx.x;
    float m = sum[c] * (1.f / NN);
    float var = sq[c] * (1.f / NN) - m * m;
    float sc = g[c] * rsqrtf(var + BN_EPS);
    scale[c] = sc;
    shift[c] = b[c] - m * sc;
}

// GEMM over 192-col affine-normalized concat(x1,x2,h). EPI: +bias, elu, stats
template <bool EPI>
__global__ void __launch_bounds__(256) k_gemm192(const float* __restrict__ x1,
                                                 const float* __restrict__ x2,
                                                 const float* __restrict__ h,
                                                 const float* __restrict__ scale,
                                                 const float* __restrict__ shift,
                                                 const float* __restrict__ W,
                                                 const float* __restrict__ bias,
                                                 float* __restrict__ out,
                                                 float* __restrict__ sum,
                                                 float* __restrict__ sq) {
    __shared__ float Wl[192 * 64];
    __shared__ float scl[192], shl[192];
    __shared__ float rs[256], rq[256];
    for (int i = threadIdx.x; i < 192 * 64; i += 256) Wl[i] = W[i];
    for (int i = threadIdx.x; i < 192; i += 256) { scl[i] = scale[i]; shl[i] = shift[i]; }
    __syncthreads();
    int wave = threadIdx.x >> 6, lane = threadIdx.x & 63;
    float s = 0, q = 0;
    for (int n = blockIdx.x * 4 + wave; n < NN; n += gridDim.x * 4) {
        float acc = 0.f;
        const float* a = x1 + (size_t)n * 64;
        #pragma unroll 16
        for (int k = 0; k < 64; k++) {
            float v = a[k] * scl[k] + shl[k];
            acc += v * Wl[k * 64 + lane];
        }
        const float* b = x2 + (size_t)n * 64;
        #pragma unroll 16
        for (int k = 0; k < 64; k++) {
            float v = b[k] * scl[64 + k] + shl[64 + k];
            acc += v * Wl[(64 + k) * 64 + lane];
        }
        const float* hh = h + (size_t)n * 64;
        #pragma unroll 16
        for (int k = 0; k < 64; k++) {
            float v = hh[k] * scl[128 + k] + shl[128 + k];
            acc += v * Wl[(128 + k) * 64 + lane];
        }
        if (EPI) {
            acc += bias[lane];
            acc = acc > 0.f ? acc : (__expf(acc) - 1.f);
            s += acc; q += acc * acc;
        }
        out[(size_t)n * 64 + lane] = acc;
    }
    if (EPI) {
        rs[threadIdx.x] = s; rq[threadIdx.x] = q;
        __syncthreads();
        if (threadIdx.x < 64) {
            int l = threadIdx.x;
            atomicAdd(&sum[l], rs[l] + rs[l + 64] + rs[l + 128] + rs[l + 192]);
            atomicAdd(&sq[l], rq[l] + rq[l + 64] + rq[l + 128] + rq[l + 192]);
        }
    }
}

// 64 -> 64: out = elu(affine(in) @ W + bias), stats
__global__ void __launch_bounds__(256) k_gemm64(const float* __restrict__ in,
                                                const float* __restrict__ scale,
                                                const float* __restrict__ shift,
                                                const float* __restrict__ W,
                                                const float* __restrict__ bias,
                                                float* __restrict__ out,
                                                float* __restrict__ sum,
                                                float* __restrict__ sq) {
    __shared__ float Wl[64 * 64];
    __shared__ float scl[64], shl[64];
    __shared__ float rs[256], rq[256];
    for (int i = threadIdx.x; i < 64 * 64; i += 256) Wl[i] = W[i];
    if (threadIdx.x < 64) { scl[threadIdx.x] = scale[threadIdx.x]; shl[threadIdx.x] = shift[threadIdx.x]; }
    __syncthreads();
    int wave = threadIdx.x >> 6, lane = threadIdx.x & 63;
    float s = 0, q = 0;
    for (int n = blockIdx.x * 4 + wave; n < NN; n += gridDim.x * 4) {
        float acc = 0.f;
        const float* a = in + (size_t)n * 64;
        #pragma unroll 16
        for (int k = 0; k < 64; k++) {
            float v = a[k] * scl[k] + shl[k];
            acc += v * Wl[k * 64 + lane];
        }
        acc += bias[lane];
        acc = acc > 0.f ? acc : (__expf(acc) - 1.f);
        out[(size_t)n * 64 + lane] = acc;
        s += acc; q += acc * acc;
    }
    rs[threadIdx.x] = s; rq[threadIdx.x] = q;
    __syncthreads();
    if (threadIdx.x < 64) {
        int l = threadIdx.x;
        atomicAdd(&sum[l], rs[l] + rs[l + 64] + rs[l + 128] + rs[l + 192]);
        atomicAdd(&sq[l], rq[l] + rq[l + 64] + rq[l + 128] + rq[l + 192]);
    }
}

// 64 -> 32: each wave handles 2 rows (lane>>5), col = lane&31
__global__ void __launch_bounds__(256) k_gemm32(const float* __restrict__ in,
                                                const float* __restrict__ scale,
                                                const float* __restrict__ shift,
                                                const float* __restrict__ W,
                                                const float* __restrict__ bias,
                                                float* __restrict__ out,
                                                float* __restrict__ sum,
                                                float* __restrict__ sq) {
    __shared__ float Wl[64 * 32];
    __shared__ float scl[64], shl[64];
    __shared__ float rs[256], rq[256];
    for (int i = threadIdx.x; i < 64 * 32; i += 256) Wl[i] = W[i];
    if (threadIdx.x < 64) { scl[threadIdx.x] = scale[threadIdx.x]; shl[threadIdx.x] = shift[threadIdx.x]; }
    __syncthreads();
    int wave = threadIdx.x >> 6, lane = threadIdx.x & 63;
    int sub = lane >> 5, c = lane & 31;
    float s = 0, q = 0;
    for (int n = blockIdx.x * 8 + wave * 2 + sub; n < NN; n += gridDim.x * 8) {
        float acc = 0.f;
        const float* a = in + (size_t)n * 64;
        #pragma unroll 16
        for (int k = 0; k < 64; k++) {
            float v = a[k] * scl[k] + shl[k];
            acc += v * Wl[k * 32 + c];
        }
        acc += bias[c];
        acc = acc > 0.f ? acc : (__expf(acc) - 1.f);
        out[(size_t)n * 32 + c] = acc;
        s += acc; q += acc * acc;
    }
    rs[threadIdx.x] = s; rq[threadIdx.x] = q;
    __syncthreads();
    if (threadIdx.x < 32) {
        float S = 0, Q = 0;
        #pragma unroll
        for (int j = 0; j < 8; j++) { S += rs[threadIdx.x + 32 * j]; Q += rq[threadIdx.x + 32 * j]; }
        atomicAdd(&sum[threadIdx.x], S);
        atomicAdd(&sq[threadIdx.x], Q);
    }
}

__global__ void k_out(const float* __restrict__ u2, const float* __restrict__ scale,
                      const float* __restrict__ shift, float* __restrict__ out) {
    int t = blockIdx.x * blockDim.x + threadIdx.x;
    if (t < NN * 32) {
        int c = t & 31;
        out[t] = u2[t] * scale[c] + shift[c];
    }
}

extern "C" void kernel_launch(void* const* d_in, const int* in_sizes, int n_in,
                              void* d_out, int out_size, void* d_ws, size_t ws_size,
                              hipStream_t stream) {
    const float* x1 = (const float*)d_in[0];
    const float* x2 = (const float*)d_in[1];
    const float* rd = (const float*)d_in[2];
    // d_in[3] = batch (unused by reference output)
    const float* mask = (const float*)d_in[4];
    const int* ei = (const int*)d_in[5];
    const int* erow = ei;
    const int* ecol = ei + NE;
    const float* conv0_w = (const float*)d_in[6];
    const float* conv0_b = (const float*)d_in[7];
    const float* conv1_w = (const float*)d_in[8];
    const float* conv1_b = (const float*)d_in[9];
    const float* bn0_g = (const float*)d_in[10];
    const float* bn0_b = (const float*)d_in[11];
    const float* bn1_g = (const float*)d_in[12];
    const float* bn1_b = (const float*)d_in[13];
    const float* mlp0_w = (const float*)d_in[14];
    const float* mlp0_b = (const float*)d_in[15];
    const float* mlp1_w = (const float*)d_in[16];
    const float* mlp1_b = (const float*)d_in[17];
    const float* mlp2_w = (const float*)d_in[18];
    const float* mlp2_b = (const float*)d_in[19];
    const float* bnm0_g = (const float*)d_in[20];
    const float* bnm0_b = (const float*)d_in[21];
    const float* bnm1_g = (const float*)d_in[22];
    const float* bnm1_b = (const float*)d_in[23];
    const float* bnm2_g = (const float*)d_in[24];
    const float* bnm2_b = (const float*)d_in[25];

    float* ws = (float*)d_ws;
    float* dis = ws + OFF_DIS;
    float* coef = ws + OFF_COEF;
    float* bufA = ws + OFF_BUFA;
    float* bufB = ws + OFF_BUFB;
    float* bufC = ws + OFF_BUFC;
    int* deg = (int*)(ws + OFF_DEG);
    float* st = ws + OFF_STATS;

    // zero accumulators: deg (ints) + all stats floats contiguous; agg buffers
    hipMemsetAsync(deg, 0, (size_t)(NN + 1920) * 4, stream);
    hipMemsetAsync(bufB, 0, (size_t)NN * 64 * 4, stream);
    hipMemsetAsync(bufC, 0, (size_t)NN * 64 * 4, stream);

    k_deg<<<(NE + 255) / 256, 256, 0, stream>>>(ecol, deg);
    k_dis<<<(NN + 255) / 256, 256, 0, stream>>>(deg, dis);
    k_coef<<<(NE + 255) / 256, 256, 0, stream>>>(erow, ecol, mask, dis, coef);
    k_xstats<<<2048, 256, 0, stream>>>(x1, x2, st);

    // conv0: lin -> scatter -> bias+elu+stats
    k_lin0<<<2048, 256, 0, stream>>>(x1, x2, rd, conv0_w, bufA);
    k_scatter<<<(NE * 64) / 256, 256, 0, stream>>>(erow, ecol, coef, bufA, bufB);
    k_postagg<<<2048, 256, 0, stream>>>(bufB, conv0_b, st + 256, st + 320);
    k_bnfin192<<<1, 192, 0, stream>>>(st, st + 256, st + 320, bn0_g, bn0_b, st + 832, st + 1024);

    // conv1: lin(bn0(concat)) -> scatter -> bias+elu+stats
    k_gemm192<false><<<2048, 256, 0, stream>>>(x1, x2, bufB, st + 832, st + 1024,
                                               conv1_w, nullptr, bufA, nullptr, nullptr);
    k_scatter<<<(NE * 64) / 256, 256, 0, stream>>>(erow, ecol, coef, bufA, bufC);
    k_postagg<<<2048, 256, 0, stream>>>(bufC, conv1_b, st + 384, st + 448);
    k_bnfin192<<<1, 192, 0, stream>>>(st, st + 384, st + 448, bn1_g, bn1_b, st + 1216, st + 1408);

    // MLP head
    k_gemm192<true><<<2048, 256, 0, stream>>>(x1, x2, bufC, st + 1216, st + 1408,
                                              mlp0_w, mlp0_b, bufA, st + 512, st + 576);
    k_bnfin<<<1, 64, 0, stream>>>(st + 512, st + 576, bnm0_g, bnm0_b, st + 1600, st + 1664);
    k_gemm64<<<2048, 256, 0, stream>>>(bufA, st + 1600, st + 1664, mlp1_w, mlp1_b,
                                       bufB, st + 640, st + 704);
    k_bnfin<<<1, 64, 0, stream>>>(st + 640, st + 704, bnm1_g, bnm1_b, st + 1728, st + 1792);
    k_gemm32<<<2048, 256, 0, stream>>>(bufB, st + 1728, st + 1792, mlp2_w, mlp2_b,
                                       bufC, st + 768, st + 800);
    k_bnfin<<<1, 32, 0, stream>>>(st + 768, st + 800, bnm2_g, bnm2_b, st + 1856, st + 1888);
    k_out<<<(NN * 32 + 255) / 256, 256, 0, stream>>>(bufC, st + 1856, st + 1888, (float*)d_out);
}

// Round 2
// 1416.704 us; speedup vs baseline: 1.4321x; 1.4321x over previous
//
#include <hip/hip_runtime.h>
#include <math.h>

#define NN 80000
#define NE 2560000
#define BN_EPS 1e-5f

// ---------------- workspace layout (float/int indices) ----------------
#define OFF_DIS     0                       // NN floats
#define OFF_ROWPTR  (OFF_DIS + NN)          // NN+2 ints (pad for alignment)
#define OFF_CURSOR  (OFF_ROWPTR + NN + 2)   // NN ints
#define OFF_DEG     (OFF_CURSOR + NN)       // NN ints
#define OFF_PERM    (OFF_DEG + NN)          // 2*NE ints (int2, 8B aligned: index is even)
#define OFF_BUFA    (OFF_PERM + 2*NE)       // NN*64 floats
#define OFF_BUFB    (OFF_BUFA + NN*64)      // NN*64 floats
#define OFF_STATS   (OFF_BUFB + NN*64)      // 1920 floats
// stats sub-offsets (relative to st)
//   0: xsum[128]   128: xsq[128]
// 256: hsum0[64]   320: hsq0[64]
// 384: hsum1[64]   448: hsq1[64]
// 512: msum0[64]   576: msq0[64]
// 640: msum1[64]   704: msq1[64]
// 768: msum2[32]   800: msq2[32]
// 832: scale0[192] 1024: shift0[192]
// 1216: scale1[192] 1408: shift1[192]
// 1600: sm0[64] 1664: sh0[64]
// 1728: sm1[64] 1792: sh1[64]
// 1856: sm2[32] 1888: sh2[32]

__global__ void k_deg(const int* __restrict__ col, int* __restrict__ deg) {
    int e = blockIdx.x * blockDim.x + threadIdx.x;
    if (e < NE) atomicAdd(&deg[col[e]], 1);
}

__global__ void k_dis(const int* __restrict__ deg, float* __restrict__ dis) {
    int i = blockIdx.x * blockDim.x + threadIdx.x;
    if (i < NN) {
        int d = deg[i];
        dis[i] = d > 0 ? rsqrtf((float)d) : 0.f;
    }
}

// single-block exclusive scan of deg -> rowptr (80000 elements, 1024 threads)
__global__ void __launch_bounds__(1024) k_scan(const int* __restrict__ deg,
                                               int* __restrict__ rowptr) {
    __shared__ int ssum[1024];
    int t = threadIdx.x;
    const int CH = (NN + 1023) / 1024;  // 79
    int beg = t * CH, end = beg + CH < NN ? beg + CH : NN;
    int s = 0;
    for (int i = beg; i < end; i++) s += deg[i];
    ssum[t] = s;
    __syncthreads();
    for (int off = 1; off < 1024; off <<= 1) {
        int v = (t >= off) ? ssum[t - off] : 0;
        __syncthreads();
        ssum[t] += v;
        __syncthreads();
    }
    int pre = (t == 0) ? 0 : ssum[t - 1];
    for (int i = beg; i < end; i++) { rowptr[i] = pre; pre += deg[i]; }
    if (t == 1023) rowptr[NN] = ssum[1023];
}

// permute edges into CSR slots; perm[slot] = (row, coef-as-int)
__global__ void k_permute(const int* __restrict__ row, const int* __restrict__ col,
                          const float* __restrict__ mask, const float* __restrict__ dis,
                          const int* __restrict__ rowptr, int* __restrict__ cursor,
                          int2* __restrict__ perm) {
    int e = blockIdx.x * blockDim.x + threadIdx.x;
    if (e < NE) {
        int r = row[e], c = col[e];
        int slot = rowptr[c] + atomicAdd(&cursor[c], 1);
        float coef = dis[r] * dis[c] * mask[e];
        perm[slot] = make_int2(r, __float_as_int(coef));
    }
}

// column sums/sumsqs of x1 (cols 0-63) and x2 (cols 64-127)
__global__ void __launch_bounds__(256) k_xstats(const float* __restrict__ x1,
                                                const float* __restrict__ x2,
                                                float* __restrict__ st) {
    int wave = threadIdx.x >> 6, lane = threadIdx.x & 63;
    float s1 = 0, q1 = 0, s2 = 0, q2 = 0;
    for (int n = blockIdx.x * 4 + wave; n < NN; n += gridDim.x * 4) {
        float a = x1[n * 64 + lane]; s1 += a; q1 += a * a;
        float b = x2[n * 64 + lane]; s2 += b; q2 += b * b;
    }
    __shared__ float red[4][256];
    red[0][threadIdx.x] = s1; red[1][threadIdx.x] = q1;
    red[2][threadIdx.x] = s2; red[3][threadIdx.x] = q2;
    __syncthreads();
    if (threadIdx.x < 64) {
        int l = threadIdx.x;
        float S1 = red[0][l] + red[0][l + 64] + red[0][l + 128] + red[0][l + 192];
        float Q1 = red[1][l] + red[1][l + 64] + red[1][l + 128] + red[1][l + 192];
        float S2 = red[2][l] + red[2][l + 64] + red[2][l + 128] + red[2][l + 192];
        float Q2 = red[3][l] + red[3][l + 64] + red[3][l + 128] + red[3][l + 192];
        atomicAdd(&st[l], S1);
        atomicAdd(&st[128 + l], Q1);
        atomicAdd(&st[64 + l], S2);
        atomicAdd(&st[192 + l], Q2);
    }
}

// out[n,c] = sum_k concat(x1,x2,rd)[n,k] * W[k,c]   (W is 144x64)
__global__ void __launch_bounds__(256) k_lin0(const float* __restrict__ x1,
                                              const float* __restrict__ x2,
                                              const float* __restrict__ rd,
                                              const float* __restrict__ W,
                                              float* __restrict__ out) {
    __shared__ float Wl[144 * 64];
    for (int i = threadIdx.x; i < 144 * 64; i += 256) Wl[i] = W[i];
    __syncthreads();
    int wave = threadIdx.x >> 6, lane = threadIdx.x & 63;
    for (int n = blockIdx.x * 4 + wave; n < NN; n += gridDim.x * 4) {
        float acc = 0.f;
        const float* a = x1 + (size_t)n * 64;
        #pragma unroll 16
        for (int k = 0; k < 64; k++) acc += a[k] * Wl[k * 64 + lane];
        const float* b = x2 + (size_t)n * 64;
        #pragma unroll 16
        for (int k = 0; k < 64; k++) acc += b[k] * Wl[(64 + k) * 64 + lane];
        const float* c = rd + (size_t)n * 16;
        #pragma unroll 16
        for (int k = 0; k < 16; k++) acc += c[k] * Wl[(128 + k) * 64 + lane];
        out[(size_t)n * 64 + lane] = acc;
    }
}

// CSR gather-aggregate: out[n,:] = elu(sum_e coef_e * h[row_e,:] + bias); fused BN stats
__global__ void __launch_bounds__(256) k_gather(const int* __restrict__ rowptr,
                                                const int2* __restrict__ perm,
                                                const float* __restrict__ h,
                                                const float* __restrict__ bias,
                                                float* __restrict__ out,
                                                float* __restrict__ sum,
                                                float* __restrict__ sq) {
    int wave = threadIdx.x >> 6, lane = threadIdx.x & 63;
    float bs = bias[lane];
    float s = 0, q = 0;
    for (int n = blockIdx.x * 4 + wave; n < NN; n += gridDim.x * 4) {
        int beg = rowptr[n], end = rowptr[n + 1];
        float acc = 0.f;
        int e = beg;
        for (; e + 4 <= end; e += 4) {
            int2 p0 = perm[e], p1 = perm[e + 1], p2 = perm[e + 2], p3 = perm[e + 3];
            float v0 = h[(size_t)p0.x * 64 + lane];
            float v1 = h[(size_t)p1.x * 64 + lane];
            float v2 = h[(size_t)p2.x * 64 + lane];
            float v3 = h[(size_t)p3.x * 64 + lane];
            acc += __int_as_float(p0.y) * v0;
            acc += __int_as_float(p1.y) * v1;
            acc += __int_as_float(p2.y) * v2;
            acc += __int_as_float(p3.y) * v3;
        }
        for (; e < end; e++) {
            int2 p = perm[e];
            acc += __int_as_float(p.y) * h[(size_t)p.x * 64 + lane];
        }
        float v = acc + bs;
        v = v > 0.f ? v : (__expf(v) - 1.f);
        out[(size_t)n * 64 + lane] = v;
        s += v; q += v * v;
    }
    __shared__ float rs[256], rq[256];
    rs[threadIdx.x] = s; rq[threadIdx.x] = q;
    __syncthreads();
    if (threadIdx.x < 64) {
        int l = threadIdx.x;
        atomicAdd(&sum[l], rs[l] + rs[l + 64] + rs[l + 128] + rs[l + 192]);
        atomicAdd(&sq[l], rq[l] + rq[l + 64] + rq[l + 128] + rq[l + 192]);
    }
}

// finalize 192-col BN: cols 0-127 from xstats, 128-191 from hstats
__global__ void k_bnfin192(const float* __restrict__ xs,
                           const float* __restrict__ hsum, const float* __restrict__ hsq,
                           const float* __restrict__ g, const float* __restrict__ b,
                           float* __restrict__ scale, float* __restrict__ shift) {
    int c = threadIdx.x;  // 192 threads
    float s = c < 128 ? xs[c] : hsum[c - 128];
    float q = c < 128 ? xs[128 + c] : hsq[c - 128];
    float m = s * (1.f / NN);
    float var = q * (1.f / NN) - m * m;
    float sc = g[c] * rsqrtf(var + BN_EPS);
    scale[c] = sc;
    shift[c] = b[c] - m * sc;
}

__global__ void k_bnfin(const float* __restrict__ sum, const float* __restrict__ sq,
                        const float* __restrict__ g, const float* __restrict__ b,
                        float* __restrict__ scale, float* __restrict__ shift) {
    int c = threadIdx.x;
    float m = sum[c] * (1.f / NN);
    float var = sq[c] * (1.f / NN) - m * m;
    float sc = g[c] * rsqrtf(var + BN_EPS);
    scale[c] = sc;
    shift[c] = b[c] - m * sc;
}

// GEMM over 192-col affine-normalized concat(x1,x2,h). EPI: +bias, elu, stats
template <bool EPI>
__global__ void __launch_bounds__(256) k_gemm192(const float* __restrict__ x1,
                                                 const float* __restrict__ x2,
                                                 const float* __restrict__ h,
                                                 const float* __restrict__ scale,
                                                 const float* __restrict__ shift,
                                                 const float* __restrict__ W,
                                                 const float* __restrict__ bias,
                                                 float* __restrict__ out,
                                                 float* __restrict__ sum,
                                                 float* __restrict__ sq) {
    __shared__ float Wl[192 * 64];
    __shared__ float scl[192], shl[192];
    __shared__ float rs[256], rq[256];
    for (int i = threadIdx.x; i < 192 * 64; i += 256) Wl[i] = W[i];
    for (int i = threadIdx.x; i < 192; i += 256) { scl[i] = scale[i]; shl[i] = shift[i]; }
    __syncthreads();
    int wave = threadIdx.x >> 6, lane = threadIdx.x & 63;
    float s = 0, q = 0;
    for (int n = blockIdx.x * 4 + wave; n < NN; n += gridDim.x * 4) {
        float acc = 0.f;
        const float* a = x1 + (size_t)n * 64;
        #pragma unroll 16
        for (int k = 0; k < 64; k++) {
            float v = a[k] * scl[k] + shl[k];
            acc += v * Wl[k * 64 + lane];
        }
        const float* b = x2 + (size_t)n * 64;
        #pragma unroll 16
        for (int k = 0; k < 64; k++) {
            float v = b[k] * scl[64 + k] + shl[64 + k];
            acc += v * Wl[(64 + k) * 64 + lane];
        }
        const float* hh = h + (size_t)n * 64;
        #pragma unroll 16
        for (int k = 0; k < 64; k++) {
            float v = hh[k] * scl[128 + k] + shl[128 + k];
            acc += v * Wl[(128 + k) * 64 + lane];
        }
        if (EPI) {
            acc += bias[lane];
            acc = acc > 0.f ? acc : (__expf(acc) - 1.f);
            s += acc; q += acc * acc;
        }
        out[(size_t)n * 64 + lane] = acc;
    }
    if (EPI) {
        rs[threadIdx.x] = s; rq[threadIdx.x] = q;
        __syncthreads();
        if (threadIdx.x < 64) {
            int l = threadIdx.x;
            atomicAdd(&sum[l], rs[l] + rs[l + 64] + rs[l + 128] + rs[l + 192]);
            atomicAdd(&sq[l], rq[l] + rq[l + 64] + rq[l + 128] + rq[l + 192]);
        }
    }
}

// 64 -> 64: out = elu(affine(in) @ W + bias), stats
__global__ void __launch_bounds__(256) k_gemm64(const float* __restrict__ in,
                                                const float* __restrict__ scale,
                                                const float* __restrict__ shift,
                                                const float* __restrict__ W,
                                                const float* __restrict__ bias,
                                                float* __restrict__ out,
                                                float* __restrict__ sum,
                                                float* __restrict__ sq) {
    __shared__ float Wl[64 * 64];
    __shared__ float scl[64], shl[64];
    __shared__ float rs[256], rq[256];
    for (int i = threadIdx.x; i < 64 * 64; i += 256) Wl[i] = W[i];
    if (threadIdx.x < 64) { scl[threadIdx.x] = scale[threadIdx.x]; shl[threadIdx.x] = shift[threadIdx.x]; }
    __syncthreads();
    int wave = threadIdx.x >> 6, lane = threadIdx.x & 63;
    float s = 0, q = 0;
    for (int n = blockIdx.x * 4 + wave; n < NN; n += gridDim.x * 4) {
        float acc = 0.f;
        const float* a = in + (size_t)n * 64;
        #pragma unroll 16
        for (int k = 0; k < 64; k++) {
            float v = a[k] * scl[k] + shl[k];
            acc += v * Wl[k * 64 + lane];
        }
        acc += bias[lane];
        acc = acc > 0.f ? acc : (__expf(acc) - 1.f);
        out[(size_t)n * 64 + lane] = acc;
        s += acc; q += acc * acc;
    }
    rs[threadIdx.x] = s; rq[threadIdx.x] = q;
    __syncthreads();
    if (threadIdx.x < 64) {
        int l = threadIdx.x;
        atomicAdd(&sum[l], rs[l] + rs[l + 64] + rs[l + 128] + rs[l + 192]);
        atomicAdd(&sq[l], rq[l] + rq[l + 64] + rq[l + 128] + rq[l + 192]);
    }
}

// 64 -> 32: each wave handles 2 rows (lane>>5), col = lane&31
__global__ void __launch_bounds__(256) k_gemm32(const float* __restrict__ in,
                                                const float* __restrict__ scale,
                                                const float* __restrict__ shift,
                                                const float* __restrict__ W,
                                                const float* __restrict__ bias,
                                                float* __restrict__ out,
                                                float* __restrict__ sum,
                                                float* __restrict__ sq) {
    __shared__ float Wl[64 * 32];
    __shared__ float scl[64], shl[64];
    __shared__ float rs[256], rq[256];
    for (int i = threadIdx.x; i < 64 * 32; i += 256) Wl[i] = W[i];
    if (threadIdx.x < 64) { scl[threadIdx.x] = scale[threadIdx.x]; shl[threadIdx.x] = shift[threadIdx.x]; }
    __syncthreads();
    int wave = threadIdx.x >> 6, lane = threadIdx.x & 63;
    int sub = lane >> 5, c = lane & 31;
    float s = 0, q = 0;
    for (int n = blockIdx.x * 8 + wave * 2 + sub; n < NN; n += gridDim.x * 8) {
        float acc = 0.f;
        const float* a = in + (size_t)n * 64;
        #pragma unroll 16
        for (int k = 0; k < 64; k++) {
            float v = a[k] * scl[k] + shl[k];
            acc += v * Wl[k * 32 + c];
        }
        acc += bias[c];
        acc = acc > 0.f ? acc : (__expf(acc) - 1.f);
        out[(size_t)n * 32 + c] = acc;
        s += acc; q += acc * acc;
    }
    rs[threadIdx.x] = s; rq[threadIdx.x] = q;
    __syncthreads();
    if (threadIdx.x < 32) {
        float S = 0, Q = 0;
        #pragma unroll
        for (int j = 0; j < 8; j++) { S += rs[threadIdx.x + 32 * j]; Q += rq[threadIdx.x + 32 * j]; }
        atomicAdd(&sum[threadIdx.x], S);
        atomicAdd(&sq[threadIdx.x], Q);
    }
}

__global__ void k_out(const float* __restrict__ u2, const float* __restrict__ scale,
                      const float* __restrict__ shift, float* __restrict__ out) {
    int t = blockIdx.x * blockDim.x + threadIdx.x;
    if (t < NN * 32) {
        int c = t & 31;
        out[t] = u2[t] * scale[c] + shift[c];
    }
}

extern "C" void kernel_launch(void* const* d_in, const int* in_sizes, int n_in,
                              void* d_out, int out_size, void* d_ws, size_t ws_size,
                              hipStream_t stream) {
    const float* x1 = (const float*)d_in[0];
    const float* x2 = (const float*)d_in[1];
    const float* rd = (const float*)d_in[2];
    // d_in[3] = batch (unused by reference output)
    const float* mask = (const float*)d_in[4];
    const int* ei = (const int*)d_in[5];
    const int* erow = ei;
    const int* ecol = ei + NE;
    const float* conv0_w = (const float*)d_in[6];
    const float* conv0_b = (const float*)d_in[7];
    const float* conv1_w = (const float*)d_in[8];
    const float* conv1_b = (const float*)d_in[9];
    const float* bn0_g = (const float*)d_in[10];
    const float* bn0_b = (const float*)d_in[11];
    const float* bn1_g = (const float*)d_in[12];
    const float* bn1_b = (const float*)d_in[13];
    const float* mlp0_w = (const float*)d_in[14];
    const float* mlp0_b = (const float*)d_in[15];
    const float* mlp1_w = (const float*)d_in[16];
    const float* mlp1_b = (const float*)d_in[17];
    const float* mlp2_w = (const float*)d_in[18];
    const float* mlp2_b = (const float*)d_in[19];
    const float* bnm0_g = (const float*)d_in[20];
    const float* bnm0_b = (const float*)d_in[21];
    const float* bnm1_g = (const float*)d_in[22];
    const float* bnm1_b = (const float*)d_in[23];
    const float* bnm2_g = (const float*)d_in[24];
    const float* bnm2_b = (const float*)d_in[25];

    float* ws = (float*)d_ws;
    float* dis = ws + OFF_DIS;
    int* rowptr = (int*)(ws + OFF_ROWPTR);
    int* cursor = (int*)(ws + OFF_CURSOR);
    int* deg = (int*)(ws + OFF_DEG);
    int2* perm = (int2*)(ws + OFF_PERM);
    float* bufA = ws + OFF_BUFA;
    float* bufB = ws + OFF_BUFB;
    float* st = ws + OFF_STATS;

    // zero: cursor+deg (contiguous 2*NN ints), stats
    hipMemsetAsync(cursor, 0, (size_t)(2 * NN) * 4, stream);
    hipMemsetAsync(st, 0, (size_t)1920 * 4, stream);

    // CSR build
    k_deg<<<(NE + 255) / 256, 256, 0, stream>>>(ecol, deg);
    k_dis<<<(NN + 255) / 256, 256, 0, stream>>>(deg, dis);
    k_scan<<<1, 1024, 0, stream>>>(deg, rowptr);
    k_permute<<<(NE + 255) / 256, 256, 0, stream>>>(erow, ecol, mask, dis, rowptr, cursor, perm);
    k_xstats<<<2048, 256, 0, stream>>>(x1, x2, st);

    // conv0: lin -> gather(+bias+elu+stats)
    k_lin0<<<2048, 256, 0, stream>>>(x1, x2, rd, conv0_w, bufA);
    k_gather<<<2048, 256, 0, stream>>>(rowptr, perm, bufA, conv0_b, bufB, st + 256, st + 320);
    k_bnfin192<<<1, 192, 0, stream>>>(st, st + 256, st + 320, bn0_g, bn0_b, st + 832, st + 1024);

    // conv1: gemm(bn0(concat)) -> gather(+bias+elu+stats)
    k_gemm192<false><<<2048, 256, 0, stream>>>(x1, x2, bufB, st + 832, st + 1024,
                                               conv1_w, nullptr, bufA, nullptr, nullptr);
    k_gather<<<2048, 256, 0, stream>>>(rowptr, perm, bufA, conv1_b, bufB, st + 384, st + 448);
    k_bnfin192<<<1, 192, 0, stream>>>(st, st + 384, st + 448, bn1_g, bn1_b, st + 1216, st + 1408);

    // MLP head
    k_gemm192<true><<<2048, 256, 0, stream>>>(x1, x2, bufB, st + 1216, st + 1408,
                                              mlp0_w, mlp0_b, bufA, st + 512, st + 576);
    k_bnfin<<<1, 64, 0, stream>>>(st + 512, st + 576, bnm0_g, bnm0_b, st + 1600, st + 1664);
    k_gemm64<<<2048, 256, 0, stream>>>(bufA, st + 1600, st + 1664, mlp1_w, mlp1_b,
                                       bufB, st + 640, st + 704);
    k_bnfin<<<1, 64, 0, stream>>>(st + 640, st + 704, bnm1_g, bnm1_b, st + 1728, st + 1792);
    k_gemm32<<<2048, 256, 0, stream>>>(bufB, st + 1728, st + 1792, mlp2_w, mlp2_b,
                                       bufA, st + 768, st + 800);
    k_bnfin<<<1, 32, 0, stream>>>(st + 768, st + 800, bnm2_g, bnm2_b, st + 1856, st + 1888);
    k_out<<<(NN * 32 + 255) / 256, 256, 0, stream>>>(bufA, st + 1856, st + 1888, (float*)d_out);
}

// Round 3
// 903.731 us; speedup vs baseline: 2.2450x; 1.5676x over previous
//
#include <hip/hip_runtime.h>
#include <math.h>

#define NN 80000
#define NE 2560000
#define BN_EPS 1e-5f

typedef __attribute__((ext_vector_type(8))) short short8;
typedef __attribute__((ext_vector_type(4))) float f32x4;

// ---------------- workspace layout (f32 index units, all 16B-aligned) ----------------
#define OFF_DIS     0                       // NN f32
#define OFF_ROWPTR  80000                   // NN+2 ints
#define OFF_CURSOR  160004                  // NN ints
#define OFF_DEG     240004                  // NN ints
#define OFF_PERM    320004                  // 2*NE ints (int2)
#define OFF_XB      (OFF_PERM + 2*NE)       // N*128 bf16 = N*64 f32
#define OFF_RDB     (OFF_XB + NN*64)        // N*32 bf16
#define OFF_B1      (OFF_RDB + NN*16)       // N*64 bf16 (or N*32 f32)
#define OFF_B2      (OFF_B1 + NN*32)
#define OFF_B3      (OFF_B2 + NN*32)
#define OFF_WP      (OFF_B3 + NN*32)        // 40960 ushorts = 20480 f32
#define OFF_BV      (OFF_WP + 20480)        // 5*64 f32
#define OFF_STATS   (OFF_BV + 320)          // 1920 f32
// stats: 0 xsum[128] /128 xsq[128] /256 h0s /320 h0q /384 h1s /448 h1q
//        /512 m0s /576 m0q /640 m1s /704 m1q /768 m2s[32] /800 m2q[32]
//        /1856 sm2[32] /1888 sh2[32]
// Wp sub-offsets (ushort units): WP0=0(10240) WP1=10240(12288) WP2=22528(12288)
//                                WP3=34816(4096) WP4=38912(2048)

__device__ __forceinline__ ushort f2b(float f) {
    union { float f; unsigned u; } x; x.f = f;
    return (ushort)((x.u + 0x7FFF + ((x.u >> 16) & 1)) >> 16);
}
__device__ __forceinline__ float b2f(ushort u) {
    union { unsigned u; float f; } x; x.u = ((unsigned)u) << 16;
    return x.f;
}

__global__ void k_deg(const int* __restrict__ col, int* __restrict__ deg) {
    int e = blockIdx.x * blockDim.x + threadIdx.x;
    if (e < NE) atomicAdd(&deg[col[e]], 1);
}

__global__ void k_dis(const int* __restrict__ deg, float* __restrict__ dis) {
    int i = blockIdx.x * blockDim.x + threadIdx.x;
    if (i < NN) {
        int d = deg[i];
        dis[i] = d > 0 ? rsqrtf((float)d) : 0.f;
    }
}

__global__ void __launch_bounds__(1024) k_scan(const int* __restrict__ deg,
                                               int* __restrict__ rowptr) {
    __shared__ int ssum[1024];
    int t = threadIdx.x;
    const int CH = (NN + 1023) / 1024;
    int beg = t * CH, end = beg + CH < NN ? beg + CH : NN;
    int s = 0;
    for (int i = beg; i < end; i++) s += deg[i];
    ssum[t] = s;
    __syncthreads();
    for (int off = 1; off < 1024; off <<= 1) {
        int v = (t >= off) ? ssum[t - off] : 0;
        __syncthreads();
        ssum[t] += v;
        __syncthreads();
    }
    int pre = (t == 0) ? 0 : ssum[t - 1];
    for (int i = beg; i < end; i++) { rowptr[i] = pre; pre += deg[i]; }
    if (t == 1023) rowptr[NN] = ssum[1023];
}

__global__ void k_permute(const int* __restrict__ row, const int* __restrict__ col,
                          const float* __restrict__ mask, const float* __restrict__ dis,
                          const int* __restrict__ rowptr, int* __restrict__ cursor,
                          int2* __restrict__ perm) {
    int e = blockIdx.x * blockDim.x + threadIdx.x;
    if (e < NE) {
        int r = row[e], c = col[e];
        int slot = rowptr[c] + atomicAdd(&cursor[c], 1);
        float coef = dis[r] * dis[c] * mask[e];
        perm[slot] = make_int2(r, __float_as_int(coef));
    }
}

// column sums/sumsqs of x1 (cols 0-63) and x2 (cols 64-127), f32 inputs
__global__ void __launch_bounds__(256) k_xstats(const float* __restrict__ x1,
                                                const float* __restrict__ x2,
                                                float* __restrict__ st) {
    int wave = threadIdx.x >> 6, lane = threadIdx.x & 63;
    float s1 = 0, q1 = 0, s2 = 0, q2 = 0;
    for (int n = blockIdx.x * 4 + wave; n < NN; n += gridDim.x * 4) {
        float a = x1[n * 64 + lane]; s1 += a; q1 += a * a;
        float b = x2[n * 64 + lane]; s2 += b; q2 += b * b;
    }
    __shared__ float red[4][256];
    red[0][threadIdx.x] = s1; red[1][threadIdx.x] = q1;
    red[2][threadIdx.x] = s2; red[3][threadIdx.x] = q2;
    __syncthreads();
    if (threadIdx.x < 64) {
        int l = threadIdx.x;
        atomicAdd(&st[l],       red[0][l] + red[0][l+64] + red[0][l+128] + red[0][l+192]);
        atomicAdd(&st[128 + l], red[1][l] + red[1][l+64] + red[1][l+128] + red[1][l+192]);
        atomicAdd(&st[64 + l],  red[2][l] + red[2][l+64] + red[2][l+128] + red[2][l+192]);
        atomicAdd(&st[192 + l], red[3][l] + red[3][l+64] + red[3][l+128] + red[3][l+192]);
    }
}

// build xb [N,128] bf16 and rdb [N,32] bf16 (cols 16-31 zero)
__global__ void __launch_bounds__(256) k_prep(const float* __restrict__ x1,
                                              const float* __restrict__ x2,
                                              const float* __restrict__ rd,
                                              ushort* __restrict__ xb,
                                              ushort* __restrict__ rdb) {
    int wave = threadIdx.x >> 6, lane = threadIdx.x & 63;
    for (int n = blockIdx.x * 4 + wave; n < NN; n += gridDim.x * 4) {
        xb[(size_t)n * 128 + lane]      = f2b(x1[(size_t)n * 64 + lane]);
        xb[(size_t)n * 128 + 64 + lane] = f2b(x2[(size_t)n * 64 + lane]);
        if (lane < 32)
            rdb[(size_t)n * 32 + lane] = lane < 16 ? f2b(rd[(size_t)n * 16 + lane]) : 0;
    }
}

// pack lin0 weights (144x64 f32, zero-padded to 160 rows) into MFMA B-frag order
__global__ void k_foldw0(const float* __restrict__ W, ushort* __restrict__ Wp) {
    for (int idx = threadIdx.x; idx < 160 * 64; idx += 256) {
        int k = idx >> 6, c = idx & 63;
        float val = k < 144 ? W[k * 64 + c] : 0.f;
        int ks = k >> 5, j = k & 7, kg = (k >> 3) & 3;
        int l = kg * 16 + (c & 15), ct = c >> 4;
        Wp[((ks * 4 + ct) * 64 + l) * 8 + j] = f2b(val);
    }
}

// BN(192) finalize + fold into packed weights and bias vector
__global__ void k_bnfold192(const float* __restrict__ xs,
                            const float* __restrict__ hsum, const float* __restrict__ hsq,
                            const float* __restrict__ g, const float* __restrict__ bnb,
                            const float* __restrict__ W,     // 192x64 f32
                            const float* __restrict__ bias,  // or null
                            ushort* __restrict__ Wp, float* __restrict__ bvec) {
    __shared__ float scale[192], shift[192];
    int t = threadIdx.x;
    if (t < 192) {
        float s = t < 128 ? xs[t] : hsum[t - 128];
        float q = t < 128 ? xs[128 + t] : hsq[t - 128];
        float m = s * (1.f / NN);
        float var = q * (1.f / NN) - m * m;
        float sc = g[t] * rsqrtf(var + BN_EPS);
        scale[t] = sc;
        shift[t] = bnb[t] - m * sc;
    }
    __syncthreads();
    for (int idx = t; idx < 192 * 64; idx += 256) {
        int k = idx >> 6, c = idx & 63;
        float val = scale[k] * W[idx];
        int ks = k >> 5, j = k & 7, kg = (k >> 3) & 3;
        int l = kg * 16 + (c & 15), ct = c >> 4;
        Wp[((ks * 4 + ct) * 64 + l) * 8 + j] = f2b(val);
    }
    if (t < 64) {
        float acc = bias ? bias[t] : 0.f;
        for (int k = 0; k < 192; k++) acc += shift[k] * W[k * 64 + t];
        bvec[t] = acc;
    }
}

// BN(64) finalize + fold (NCw = 64 or 32 output cols)
__global__ void k_bnfold64(const float* __restrict__ sum, const float* __restrict__ sq,
                           const float* __restrict__ g, const float* __restrict__ bnb,
                           const float* __restrict__ W, const float* __restrict__ bias,
                           ushort* __restrict__ Wp, float* __restrict__ bvec, int NCw) {
    __shared__ float scale[64], shift[64];
    int t = threadIdx.x;
    if (t < 64) {
        float m = sum[t] * (1.f / NN);
        float var = sq[t] * (1.f / NN) - m * m;
        float sc = g[t] * rsqrtf(var + BN_EPS);
        scale[t] = sc;
        shift[t] = bnb[t] - m * sc;
    }
    __syncthreads();
    int NCOLT = NCw >> 4;
    for (int idx = t; idx < 64 * NCw; idx += 256) {
        int k = idx / NCw, c = idx % NCw;
        float val = scale[k] * W[idx];
        int ks = k >> 5, j = k & 7, kg = (k >> 3) & 3;
        int l = kg * 16 + (c & 15), ct = c >> 4;
        Wp[((ks * NCOLT + ct) * 64 + l) * 8 + j] = f2b(val);
    }
    if (t < NCw) {
        float acc = bias[t];
        for (int k = 0; k < 64; k++) acc += shift[k] * W[k * NCw + t];
        bvec[t] = acc;
    }
}

__global__ void k_bnfin(const float* __restrict__ sum, const float* __restrict__ sq,
                        const float* __restrict__ g, const float* __restrict__ b,
                        float* __restrict__ scale, float* __restrict__ shift) {
    int c = threadIdx.x;
    float m = sum[c] * (1.f / NN);
    float var = sq[c] * (1.f / NN) - m * m;
    float sc = g[c] * rsqrtf(var + BN_EPS);
    scale[c] = sc;
    shift[c] = b[c] - m * sc;
}

// ---------------- MFMA GEMM: out[N, NC] = A[N, K] @ Wp + bvec ----------------
// A split across A1 (first KS1*32 k's, row-stride S1) and A2 (rest, stride S2).
// 4 waves/block; wave = 16 rows x NC cols. EPI: +elu + column stats. OUTF32: f32 out.
template <int KSTEPS, int NCOLT, int KS1, int S1, int S2, bool EPI, bool OUTF32>
__global__ void __launch_bounds__(256) k_mfma(const ushort* __restrict__ A1,
                                              const ushort* __restrict__ A2,
                                              const ushort* __restrict__ Wp,
                                              const float* __restrict__ bvec,
                                              void* __restrict__ out,
                                              float* __restrict__ sum,
                                              float* __restrict__ sq) {
    const int NC = NCOLT * 16;
    __shared__ float cs[NC], cq[NC];
    int wave = threadIdx.x >> 6, lane = threadIdx.x & 63;
    int r0 = lane & 15, kg = lane >> 4;
    int rbase = blockIdx.x * 64 + wave * 16;
    if (EPI) {
        if (threadIdx.x < NC) { cs[threadIdx.x] = 0.f; cq[threadIdx.x] = 0.f; }
        __syncthreads();
    }
    f32x4 acc[NCOLT];
    #pragma unroll
    for (int ct = 0; ct < NCOLT; ct++) acc[ct] = (f32x4){0.f, 0.f, 0.f, 0.f};
    #pragma unroll
    for (int ks = 0; ks < KSTEPS; ks++) {
        const ushort* src = (ks < KS1)
            ? A1 + (size_t)(rbase + r0) * S1 + ks * 32 + kg * 8
            : A2 + (size_t)(rbase + r0) * S2 + (ks - KS1) * 32 + kg * 8;
        short8 a = *reinterpret_cast<const short8*>(src);
        #pragma unroll
        for (int ct = 0; ct < NCOLT; ct++) {
            short8 b = *reinterpret_cast<const short8*>(Wp + ((size_t)(ks * NCOLT + ct) * 64 + lane) * 8);
            acc[ct] = __builtin_amdgcn_mfma_f32_16x16x32_bf16(a, b, acc[ct], 0, 0, 0);
        }
    }
    float ss[NCOLT], qq[NCOLT];
    #pragma unroll
    for (int ct = 0; ct < NCOLT; ct++) {
        int c = ct * 16 + r0;
        float bv = bvec[c];
        ss[ct] = 0.f; qq[ct] = 0.f;
        #pragma unroll
        for (int r = 0; r < 4; r++) {
            int row = rbase + kg * 4 + r;
            float v = acc[ct][r] + bv;
            if (EPI) {
                v = v > 0.f ? v : (__expf(v) - 1.f);
                ss[ct] += v; qq[ct] += v * v;
            }
            if (OUTF32) ((float*)out)[(size_t)row * NC + c] = v;
            else        ((ushort*)out)[(size_t)row * NC + c] = f2b(v);
        }
    }
    if (EPI) {
        #pragma unroll
        for (int ct = 0; ct < NCOLT; ct++) {
            int c = ct * 16 + r0;
            atomicAdd(&cs[c], ss[ct]);
            atomicAdd(&cq[c], qq[ct]);
        }
        __syncthreads();
        if (threadIdx.x < NC) {
            atomicAdd(&sum[threadIdx.x], cs[threadIdx.x]);
            atomicAdd(&sq[threadIdx.x], cq[threadIdx.x]);
        }
    }
}

// CSR gather-aggregate over bf16 rows: out = bf16(elu(sum coef*h[row] + bias)); stats
__global__ void __launch_bounds__(256) k_gather(const int* __restrict__ rowptr,
                                                const int2* __restrict__ perm,
                                                const ushort* __restrict__ h,
                                                const float* __restrict__ bias,
                                                ushort* __restrict__ out,
                                                float* __restrict__ sum,
                                                float* __restrict__ sq) {
    int wave = threadIdx.x >> 6, lane = threadIdx.x & 63;
    float bs = bias[lane];
    float s = 0, q = 0;
    for (int n = blockIdx.x * 4 + wave; n < NN; n += gridDim.x * 4) {
        int beg = rowptr[n], end = rowptr[n + 1];
        float acc = 0.f;
        int e = beg;
        for (; e + 4 <= end; e += 4) {
            int2 p0 = perm[e], p1 = perm[e + 1], p2 = perm[e + 2], p3 = perm[e + 3];
            float v0 = b2f(h[(size_t)p0.x * 64 + lane]);
            float v1 = b2f(h[(size_t)p1.x * 64 + lane]);
            float v2 = b2f(h[(size_t)p2.x * 64 + lane]);
            float v3 = b2f(h[(size_t)p3.x * 64 + lane]);
            acc += __int_as_float(p0.y) * v0;
            acc += __int_as_float(p1.y) * v1;
            acc += __int_as_float(p2.y) * v2;
            acc += __int_as_float(p3.y) * v3;
        }
        for (; e < end; e++) {
            int2 p = perm[e];
            acc += __int_as_float(p.y) * b2f(h[(size_t)p.x * 64 + lane]);
        }
        float v = acc + bs;
        v = v > 0.f ? v : (__expf(v) - 1.f);
        out[(size_t)n * 64 + lane] = f2b(v);
        s += v; q += v * v;
    }
    __shared__ float rs[256], rq[256];
    rs[threadIdx.x] = s; rq[threadIdx.x] = q;
    __syncthreads();
    if (threadIdx.x < 64) {
        int l = threadIdx.x;
        atomicAdd(&sum[l], rs[l] + rs[l + 64] + rs[l + 128] + rs[l + 192]);
        atomicAdd(&sq[l],  rq[l] + rq[l + 64] + rq[l + 128] + rq[l + 192]);
    }
}

__global__ void k_out(const float* __restrict__ u2, const float* __restrict__ scale,
                      const float* __restrict__ shift, float* __restrict__ out) {
    int t = blockIdx.x * blockDim.x + threadIdx.x;
    if (t < NN * 32) {
        int c = t & 31;
        out[t] = u2[t] * scale[c] + shift[c];
    }
}

extern "C" void kernel_launch(void* const* d_in, const int* in_sizes, int n_in,
                              void* d_out, int out_size, void* d_ws, size_t ws_size,
                              hipStream_t stream) {
    const float* x1 = (const float*)d_in[0];
    const float* x2 = (const float*)d_in[1];
    const float* rd = (const float*)d_in[2];
    const float* mask = (const float*)d_in[4];
    const int* ei = (const int*)d_in[5];
    const int* erow = ei;
    const int* ecol = ei + NE;
    const float* conv0_w = (const float*)d_in[6];
    const float* conv0_b = (const float*)d_in[7];
    const float* conv1_w = (const float*)d_in[8];
    const float* conv1_b = (const float*)d_in[9];
    const float* bn0_g = (const float*)d_in[10];
    const float* bn0_b = (const float*)d_in[11];
    const float* bn1_g = (const float*)d_in[12];
    const float* bn1_b = (const float*)d_in[13];
    const float* mlp0_w = (const float*)d_in[14];
    const float* mlp0_b = (const float*)d_in[15];
    const float* mlp1_w = (const float*)d_in[16];
    const float* mlp1_b = (const float*)d_in[17];
    const float* mlp2_w = (const float*)d_in[18];
    const float* mlp2_b = (const float*)d_in[19];
    const float* bnm0_g = (const float*)d_in[20];
    const float* bnm0_b = (const float*)d_in[21];
    const float* bnm1_g = (const float*)d_in[22];
    const float* bnm1_b = (const float*)d_in[23];
    const float* bnm2_g = (const float*)d_in[24];
    const float* bnm2_b = (const float*)d_in[25];

    float* ws = (float*)d_ws;
    float* dis = ws + OFF_DIS;
    int* rowptr = (int*)(ws + OFF_ROWPTR);
    int* cursor = (int*)(ws + OFF_CURSOR);
    int* deg = (int*)(ws + OFF_DEG);
    int2* perm = (int2*)(ws + OFF_PERM);
    ushort* xb = (ushort*)(ws + OFF_XB);
    ushort* rdb = (ushort*)(ws + OFF_RDB);
    ushort* B1 = (ushort*)(ws + OFF_B1);
    ushort* B2 = (ushort*)(ws + OFF_B2);
    ushort* B3 = (ushort*)(ws + OFF_B3);
    ushort* wp = (ushort*)(ws + OFF_WP);
    ushort* WP0 = wp, *WP1 = wp + 10240, *WP2 = wp + 22528, *WP3 = wp + 34816, *WP4 = wp + 38912;
    float* bv = ws + OFF_BV;   // BV0=bv (zeros), BV1=bv+64, ... BV4=bv+256
    float* st = ws + OFF_STATS;

    hipMemsetAsync(cursor, 0, (size_t)(2 * NN) * 4, stream);               // cursor+deg
    hipMemsetAsync(bv, 0, (size_t)(320 + 1920) * 4, stream);               // bvecs+stats

    // CSR build + static prep
    k_deg<<<(NE + 255) / 256, 256, 0, stream>>>(ecol, deg);
    k_dis<<<(NN + 255) / 256, 256, 0, stream>>>(deg, dis);
    k_scan<<<1, 1024, 0, stream>>>(deg, rowptr);
    k_permute<<<(NE + 255) / 256, 256, 0, stream>>>(erow, ecol, mask, dis, rowptr, cursor, perm);
    k_xstats<<<1024, 256, 0, stream>>>(x1, x2, st);
    k_prep<<<1024, 256, 0, stream>>>(x1, x2, rd, xb, rdb);
    k_foldw0<<<1, 256, 0, stream>>>(conv0_w, WP0);

    const int GB = NN / 64;  // 1250 MFMA blocks

    // conv0: lin0 (K=160 padded) -> gather(+bias+elu+stats)
    k_mfma<5, 4, 4, 128, 32, false, false><<<GB, 256, 0, stream>>>(xb, rdb, WP0, bv, B1, nullptr, nullptr);
    k_gather<<<2048, 256, 0, stream>>>(rowptr, perm, B1, conv0_b, B2, st + 256, st + 320);
    k_bnfold192<<<1, 256, 0, stream>>>(st, st + 256, st + 320, bn0_g, bn0_b, conv1_w, nullptr, WP1, bv + 64);

    // conv1: gemm(K=192, BN0-folded) -> gather
    k_mfma<6, 4, 4, 128, 64, false, false><<<GB, 256, 0, stream>>>(xb, B2, WP1, bv + 64, B1, nullptr, nullptr);
    k_gather<<<2048, 256, 0, stream>>>(rowptr, perm, B1, conv1_b, B3, st + 384, st + 448);
    k_bnfold192<<<1, 256, 0, stream>>>(st, st + 384, st + 448, bn1_g, bn1_b, mlp0_w, mlp0_b, WP2, bv + 128);

    // MLP head
    k_mfma<6, 4, 4, 128, 64, true, false><<<GB, 256, 0, stream>>>(xb, B3, WP2, bv + 128, B2, st + 512, st + 576);
    k_bnfold64<<<1, 256, 0, stream>>>(st + 512, st + 576, bnm0_g, bnm0_b, mlp1_w, mlp1_b, WP3, bv + 192, 64);
    k_mfma<2, 4, 2, 64, 64, true, false><<<GB, 256, 0, stream>>>(B2, nullptr, WP3, bv + 192, B1, st + 640, st + 704);
    k_bnfold64<<<1, 256, 0, stream>>>(st + 640, st + 704, bnm1_g, bnm1_b, mlp2_w, mlp2_b, WP4, bv + 256, 32);
    k_mfma<2, 2, 2, 64, 64, true, true><<<GB, 256, 0, stream>>>(B1, nullptr, WP4, bv + 256, B3, st + 768, st + 800);
    k_bnfin<<<1, 32, 0, stream>>>(st + 768, st + 800, bnm2_g, bnm2_b, st + 1856, st + 1888);
    k_out<<<(NN * 32 + 255) / 256, 256, 0, stream>>>((const float*)B3, st + 1856, st + 1888, (float*)d_out);
}